// Round 13
// baseline (178.556 us; speedup 1.0000x reference)
//
#include <hip/hip_runtime.h>
#include <hip/hip_bf16.h>
#include <math.h>

// NetVLAD, MI355X gfx950. bf16 MFMA GEMMs, fp32 elsewhere.
// R12: k1 main loop barrier-free (register fragments direct from global,
// sumsq via shfl); k3b folded into k3a (global norm == 1/8 analytically).
#define N_B   32
#define C_DIM 512
#define K_DIM 64
#define HW    1200
#define PTILE 32
#define NPT   38      // ceil(1200/32)
#define ASLOT 40

typedef __attribute__((ext_vector_type(8))) short bf16x8;  // 8 bf16 in 4 VGPRs
typedef __attribute__((ext_vector_type(4))) float f32x4;

static __device__ inline short f2bf(float f) {
  __hip_bfloat16 h = __float2bfloat16(f);   // RNE
  union { __hip_bfloat16 b; short s; } u; u.b = h; return u.s;
}

// ---------------------------------------------------------------------------
// k1: logits = W(64x512) @ xn(512x32p) via MFMA. Grid 32n x 38 ptiles = 1216
// blocks, 256 thr (4 waves; wave wv owns k-rows [16wv,16wv+16)).
// Main loop has NO LDS and NO barriers: each wave loads W fragments (L2-hot)
// and its x B-fragments straight to registers; per-pixel sumsq accumulates in
// the same pass and reduces across the 4 lane-groups with shfl_xor.
// Epilogue (softmax over 64 k per pixel) exchanges via LDS slog (3 barriers).
// Stores a_scaled = softmax_a * invnorm (bf16): sum_h a*(x*inv)==sum_h (a*inv)*x.
// ---------------------------------------------------------------------------
__global__ __launch_bounds__(256) void k1_logits_softmax(
    const float* __restrict__ x, const float* __restrict__ w,
    unsigned short* __restrict__ a_out, float* __restrict__ asum_part)
{
  __shared__ float slog[64 * 36];   // [k][p] padded
  __shared__ float sred[8 * 32];
  __shared__ float pinv[32], pmax[32], psum[32];

  const int tid  = threadIdx.x;
  const int lane = tid & 63;
  const int wv   = tid >> 6;
  const int n    = blockIdx.x / NPT;
  const int tile = blockIdx.x % NPT;
  const int p0   = tile * PTILE;

  const int lr = lane & 15;         // fragment row/col index
  const int lg = lane >> 4;         // k-slice group 0..3
  const int kw = wv * 16;

  const float* xb = x + (size_t)n * C_DIM * HW;
  const int pA = p0 + lr;           // pixel for acc0 column lr
  const int pB = p0 + 16 + lr;      // pixel for acc1 column lr
  const bool vA = pA < HW, vB = pB < HW;

  const float* wrow = w + (size_t)(kw + lr) * C_DIM + lg * 8;

  f32x4 acc0 = {0.f, 0.f, 0.f, 0.f};
  f32x4 acc1 = {0.f, 0.f, 0.f, 0.f};
  float ssqA = 0.f, ssqB = 0.f;

#pragma unroll 4
  for (int c0 = 0; c0 < C_DIM; c0 += 32) {      // 16 K-chunks of 32 c
    // A-fragment: W[kw+lr][c0+lg*8 .. +8] (contiguous, float4-aligned, L2-hot)
    float4 w0 = *(const float4*)(wrow + c0);
    float4 w1 = *(const float4*)(wrow + c0 + 4);
    bf16x8 af;
    af[0]=f2bf(w0.x); af[1]=f2bf(w0.y); af[2]=f2bf(w0.z); af[3]=f2bf(w0.w);
    af[4]=f2bf(w1.x); af[5]=f2bf(w1.y); af[6]=f2bf(w1.z); af[7]=f2bf(w1.w);
    // B-fragments: x[c][pA], x[c][pB] for c = c0+lg*8+j (coalesced over lr)
    bf16x8 b0, b1;
    const float* xc = xb + (size_t)(c0 + lg * 8) * HW;
#pragma unroll
    for (int j = 0; j < 8; ++j) {
      float xA = vA ? xc[(size_t)j * HW + pA] : 0.f;
      float xB = vB ? xc[(size_t)j * HW + pB] : 0.f;
      ssqA += xA * xA;
      ssqB += xB * xB;
      b0[j] = f2bf(xA);
      b1[j] = f2bf(xB);
    }
    acc0 = __builtin_amdgcn_mfma_f32_16x16x32_bf16(af, b0, acc0, 0, 0, 0);
    acc1 = __builtin_amdgcn_mfma_f32_16x16x32_bf16(af, b1, acc1, 0, 0, 0);
  }

  // per-pixel sumsq: lanes {lr, 16+lr, 32+lr, 48+lr} hold the 4 c-slices
  ssqA += __shfl_xor(ssqA, 16); ssqA += __shfl_xor(ssqA, 32);
  ssqB += __shfl_xor(ssqB, 16); ssqB += __shfl_xor(ssqB, 32);
  const float ivA = 1.f / fmaxf(sqrtf(ssqA), 1e-12f);  // torch F.normalize eps
  const float ivB = 1.f / fmaxf(sqrtf(ssqB), 1e-12f);
  if (wv == 0 && lg == 0) { pinv[lr] = ivA; pinv[16 + lr] = ivB; }

  // scaled logits -> slog[k][p]   (D layout: row = lg*4+r, col = lr; m89)
#pragma unroll
  for (int r = 0; r < 4; ++r) {
    slog[(kw + lg * 4 + r) * 36 + lr]      = acc0[r] * ivA;
    slog[(kw + lg * 4 + r) * 36 + 16 + lr] = acc1[r] * ivB;
  }
  __syncthreads();

  // column softmax over 64 k: thread owns (p = tid&31, 8 k's)
  {
    const int p = tid & 31;
    const int kg = tid >> 5;
    float e[8];
    float m = -1e30f;
#pragma unroll
    for (int j = 0; j < 8; ++j) { e[j] = slog[(kg * 8 + j) * 36 + p]; m = fmaxf(m, e[j]); }
    sred[kg * 32 + p] = m;
    __syncthreads();
    if (tid < 32) {
      float mm = sred[tid];
#pragma unroll
      for (int g = 1; g < 8; ++g) mm = fmaxf(mm, sred[g * 32 + tid]);
      pmax[tid] = mm;
    }
    __syncthreads();
    const float M = pmax[p];
    float s = 0.f;
#pragma unroll
    for (int j = 0; j < 8; ++j) { e[j] = __expf(e[j] - M); s += e[j]; }
    sred[kg * 32 + p] = s;
    __syncthreads();
    if (tid < 32) {
      float ss = 0.f;
#pragma unroll
      for (int g = 0; g < 8; ++g) ss += sred[g * 32 + tid];
      psum[tid] = 1.f / ss;
    }
    __syncthreads();
    const float sc = psum[p];
    const float iv = pinv[p];
    const bool pv = (p0 + p) < HW;
#pragma unroll
    for (int j = 0; j < 8; ++j) {
      float av = e[j] * sc;                 // true softmax value (for asum)
      float t = pv ? av : 0.f;
#pragma unroll
      for (int off = 16; off > 0; off >>= 1) t += __shfl_xor(t, off);
      if (p == 0) asum_part[((size_t)n * K_DIM + kg * 8 + j) * ASLOT + tile] = t;
      if (pv) a_out[((size_t)n * K_DIM + kg * 8 + j) * HW + p0 + p] =
                  (unsigned short)f2bf(av * iv);   // a*inv folded for k2
    }
  }
}

// ---------------------------------------------------------------------------
// k2: vlad[k][c] = sum_h a_scaled[k][h] * x[c][h] via MFMA, fragments straight
// from global (h contiguous for both operands -> no LDS).
// Grid 32n * 16ct * 2half = 1024 blocks, 256 thr; wave = 16k x 32c strip.
// ---------------------------------------------------------------------------
__global__ __launch_bounds__(256) void k2_vlad_gemm(
    const float* __restrict__ x, const unsigned short* __restrict__ a_in,
    float* __restrict__ part)
{
  const int tid  = threadIdx.x;
  const int lane = tid & 63;
  const int wv   = tid >> 6;
  const int b    = blockIdx.x;
  const int half = b & 1;
  const int ct   = (b >> 1) & 15;
  const int n    = b >> 5;
  const int c0   = ct * 32;
  const int hb   = half * 600;
  const int k0   = wv * 16;
  const int lr = lane & 15, lg = lane >> 4;

  const float* xb          = x    + (size_t)n * C_DIM * HW;
  const unsigned short* ab = a_in + (size_t)n * K_DIM * HW;

  f32x4 acc0 = {0,0,0,0}, acc1 = {0,0,0,0};

#pragma unroll 2
  for (int hc = 0; hc < 600; hc += 32) {
    const int hrel = hc + lg * 8;
    const bool gv = hrel < 600;          // tail chunk: lane-group 3 invalid
    const int h = hb + hrel;

    bf16x8 af;
    bf16x8 bx0, bx1;
    if (gv) {
      af = *(const bf16x8*)(ab + (size_t)(k0 + lr) * HW + h);
      {
        const float* xp = xb + (size_t)(c0 + lr) * HW + h;
        float4 x0 = *(const float4*)xp;
        float4 x1 = *(const float4*)(xp + 4);
        bx0[0]=f2bf(x0.x); bx0[1]=f2bf(x0.y); bx0[2]=f2bf(x0.z); bx0[3]=f2bf(x0.w);
        bx0[4]=f2bf(x1.x); bx0[5]=f2bf(x1.y); bx0[6]=f2bf(x1.z); bx0[7]=f2bf(x1.w);
      }
      {
        const float* xp = xb + (size_t)(c0 + 16 + lr) * HW + h;
        float4 x0 = *(const float4*)xp;
        float4 x1 = *(const float4*)(xp + 4);
        bx1[0]=f2bf(x0.x); bx1[1]=f2bf(x0.y); bx1[2]=f2bf(x0.z); bx1[3]=f2bf(x0.w);
        bx1[4]=f2bf(x1.x); bx1[5]=f2bf(x1.y); bx1[6]=f2bf(x1.z); bx1[7]=f2bf(x1.w);
      }
    } else {
#pragma unroll
      for (int j = 0; j < 8; ++j) { af[j] = 0; bx0[j] = 0; bx1[j] = 0; }
    }
    acc0 = __builtin_amdgcn_mfma_f32_16x16x32_bf16(af, bx0, acc0, 0, 0, 0);
    acc1 = __builtin_amdgcn_mfma_f32_16x16x32_bf16(af, bx1, acc1, 0, 0, 0);
  }

  float* pb = part + (((size_t)half * N_B + n) * K_DIM) * C_DIM;
#pragma unroll
  for (int r = 0; r < 4; ++r) {
    pb[(size_t)(k0 + lg * 4 + r) * C_DIM + c0 + lr]      = acc0[r];
    pb[(size_t)(k0 + lg * 4 + r) * C_DIM + c0 + 16 + lr] = acc1[r];
  }
}

// ---------------------------------------------------------------------------
// k3a: v = part0 + part1 - asum*centroid; intra-normalize over C and apply
// the global 1/sqrt(K)=0.125 scale (rows are unit-norm => global norm == 8
// to ~1e-7 relative; folding it is ~1e-8 absolute on the output).
// Grid 2048 blocks, 128 threads (4 c each).
// ---------------------------------------------------------------------------
__global__ __launch_bounds__(128) void k3a_intranorm(
    const float* __restrict__ part, const float* __restrict__ cent,
    const float* __restrict__ asum_part, float* __restrict__ out)
{
  const int nk = blockIdx.x;
  const int n = nk >> 6, k = nk & 63;
  const int tid = threadIdx.x;

  __shared__ float sasum;
  __shared__ float wss[2];

  float t = (tid < NPT) ? asum_part[(size_t)nk * ASLOT + tid] : 0.f;
  if (tid < 64) {
#pragma unroll
    for (int off = 32; off > 0; off >>= 1) t += __shfl_xor(t, off);
    if (tid == 0) sasum = t;
  }
  __syncthreads();
  const float asum = sasum;

  const float* p0 = part + ((size_t)n * K_DIM + k) * C_DIM;
  const float* p1 = part + ((size_t)(N_B + n) * K_DIM + k) * C_DIM;
  const float* cb = cent + (size_t)k * C_DIM;

  float4 a4 = *(const float4*)&p0[tid * 4];
  float4 b4 = *(const float4*)&p1[tid * 4];
  float4 c4 = *(const float4*)&cb[tid * 4];
  float4 v;
  v.x = a4.x + b4.x - asum * c4.x;
  v.y = a4.y + b4.y - asum * c4.y;
  v.z = a4.z + b4.z - asum * c4.z;
  v.w = a4.w + b4.w - asum * c4.w;

  float ss = v.x * v.x + v.y * v.y + v.z * v.z + v.w * v.w;
#pragma unroll
  for (int off = 32; off > 0; off >>= 1) ss += __shfl_xor(ss, off);
  if ((tid & 63) == 0) wss[tid >> 6] = ss;
  __syncthreads();
  float tot = wss[0] + wss[1];
  float inv = 0.125f / fmaxf(sqrtf(tot), 1e-12f);   // intra-norm * global-norm

  float4 o = make_float4(v.x * inv, v.y * inv, v.z * inv, v.w * inv);
  *(float4*)&out[(size_t)n * (K_DIM * C_DIM) + k * C_DIM + tid * 4] = o;
}

// ---------------------------------------------------------------------------
extern "C" void kernel_launch(void* const* d_in, const int* in_sizes, int n_in,
                              void* d_out, int out_size, void* d_ws, size_t ws_size,
                              hipStream_t stream) {
  (void)in_sizes; (void)n_in; (void)out_size; (void)ws_size;
  const float* x    = (const float*)d_in[0];   // [32,512,30,40]
  const float* w    = (const float*)d_in[1];   // [64,512]
  const float* cent = (const float*)d_in[2];   // [64,512]
  float* out = (float*)d_out;

  // workspace layout (bytes), all 16B-aligned
  char* ws = (char*)d_ws;
  unsigned short* a_buf = (unsigned short*)(ws);        //  4,915,200 (bf16 a*inv)
  float* asum_p   = (float*)(ws + 4915200);             //    327,680
  float* part     = (float*)(ws + 5242880);             // 16,777,216

  k1_logits_softmax<<<N_B * NPT, 256, 0, stream>>>(x, w, a_buf, asum_p);
  k2_vlad_gemm<<<N_B * 32, 256, 0, stream>>>(x, a_buf, part);
  k3a_intranorm<<<N_B * K_DIM, 128, 0, stream>>>(part, cent, asum_p, out);
}